// Round 1
// baseline (98.284 us; speedup 1.0000x reference)
//
#include <hip/hip_runtime.h>

typedef __bf16 bf16x8 __attribute__((ext_vector_type(8)));
typedef float f32x4 __attribute__((ext_vector_type(4)));
typedef unsigned short u16x8 __attribute__((ext_vector_type(8)));

static __device__ __forceinline__ unsigned short f2bf(float f){
  unsigned int u = __builtin_bit_cast(unsigned int, f);
  u = (u + 0x7fffu + ((u >> 16) & 1u)) >> 16;
  return (unsigned short)u;
}

static __device__ __forceinline__ f32x4 mfma16(bf16x8 a, bf16x8 b, f32x4 c){
  return __builtin_amdgcn_mfma_f32_16x16x32_bf16(a, b, c, 0, 0, 0);
}

// B-fragment for mfma_f32_16x16x32_bf16: lane holds B[k][col] with
// col=(lane&15)+16*t, k=8*(lane>>4)+j+32*cc, j=0..7. W is row-major [64][64].
static __device__ __forceinline__ bf16x8 load_bfrag(const float* __restrict__ W, int lane, int t, int cc){
  const int col = (lane & 15) + 16 * t;
  const int k0  = 8 * (lane >> 4) + 32 * cc;
  u16x8 v;
#pragma unroll
  for (int j = 0; j < 8; ++j) v[j] = f2bf(W[(k0 + j) * 64 + col]);
  return __builtin_bit_cast(bf16x8, v);
}

#define PTS_PER_BLOCK 16

__global__ __launch_bounds__(64, 1) void pt_fused(
    const float* __restrict__ xn, const float* __restrict__ p, const float* __restrict__ pn,
    const float* __restrict__ kW1, const float* __restrict__ kb1,
    const float* __restrict__ kW2, const float* __restrict__ kb2,
    const float* __restrict__ vW1, const float* __restrict__ vb1,
    const float* __restrict__ vW2, const float* __restrict__ vb2,
    const float* __restrict__ pW1, const float* __restrict__ pb1,
    const float* __restrict__ pW2, const float* __restrict__ pb2,
    float* __restrict__ out)
{
  const int lane = threadIdx.x;   // 0..63
  const int ln   = lane & 15;
  const int g    = lane >> 4;

  // staging tiles [16 rows][64 ch] bf16, XOR-swizzled: idx = n*64 + (c ^ ((n&7)<<3))
  __shared__ unsigned short sK[1024] __attribute__((aligned(16)));
  __shared__ unsigned short sV[1024] __attribute__((aligned(16)));
  __shared__ unsigned short sP[1024] __attribute__((aligned(16)));

  // ---- weights as register B-fragments ----
  bf16x8 wk1[4][2], wk2[4][2], wv1[4][2], wv2[4][2], wp2[4][2], wp1t[4];
#pragma unroll
  for (int t = 0; t < 4; ++t){
#pragma unroll
    for (int cc = 0; cc < 2; ++cc){
      wk1[t][cc] = load_bfrag(kW1, lane, t, cc);
      wk2[t][cc] = load_bfrag(kW2, lane, t, cc);
      wv1[t][cc] = load_bfrag(vW1, lane, t, cc);
      wv2[t][cc] = load_bfrag(vW2, lane, t, cc);
      wp2[t][cc] = load_bfrag(pW2, lane, t, cc);
    }
  }
  // pW1 is [3][64]; K=32 fragment with rows 3..31 zero (only lane group 0 holds data)
#pragma unroll
  for (int t = 0; t < 4; ++t){
    u16x8 v;
#pragma unroll
    for (int j = 0; j < 8; ++j) v[j] = 0;
    if (g == 0){
#pragma unroll
      for (int j = 0; j < 3; ++j) v[j] = f2bf(pW1[j * 64 + ln + 16 * t]);
    }
    wp1t[t] = __builtin_bit_cast(bf16x8, v);
  }

  // biases in C/D layout: col = ln + 16t (rows share the same bias)
  float bk1[4], bk2[4], bv1[4], bv2[4], bp1[4], bp2[4];
#pragma unroll
  for (int t = 0; t < 4; ++t){
    const int c = ln + 16 * t;
    bk1[t] = kb1[c]; bk2[t] = kb2[c];
    bv1[t] = vb1[c]; bv2[t] = vb2[c];
    bp1[t] = pb1[c]; bp2[t] = pb2[c];
  }

  const size_t p0 = (size_t)blockIdx.x * PTS_PER_BLOCK;

  // ---- software prefetch of point 0 (xn tile + pn row) ----
  float4 nx0, nx1, nx2, nx3;
  float npn0, npn1, npn2;
  {
    const float* xp = xn + p0 * 1024 + (size_t)ln * 64 + g * 8;
    nx0 = *(const float4*)(xp + 0);
    nx1 = *(const float4*)(xp + 4);
    nx2 = *(const float4*)(xp + 32);
    nx3 = *(const float4*)(xp + 36);
    const float* q = pn + p0 * 48 + ln * 3;
    npn0 = q[0]; npn1 = q[1]; npn2 = q[2];
  }

#pragma unroll 1
  for (int i = 0; i < PTS_PER_BLOCK; ++i){
    const size_t pt = p0 + i;

    // consume prefetched data
    float cx[16];
    cx[0]=nx0.x; cx[1]=nx0.y; cx[2]=nx0.z;  cx[3]=nx0.w;
    cx[4]=nx1.x; cx[5]=nx1.y; cx[6]=nx1.z;  cx[7]=nx1.w;
    cx[8]=nx2.x; cx[9]=nx2.y; cx[10]=nx2.z; cx[11]=nx2.w;
    cx[12]=nx3.x; cx[13]=nx3.y; cx[14]=nx3.z; cx[15]=nx3.w;
    const float pnx = npn0, pny = npn1, pnz = npn2;

    // issue next point's loads early (hide HBM latency under compute)
    if (i + 1 < PTS_PER_BLOCK){
      const float* xp = xn + (pt + 1) * 1024 + (size_t)ln * 64 + g * 8;
      nx0 = *(const float4*)(xp + 0);
      nx1 = *(const float4*)(xp + 4);
      nx2 = *(const float4*)(xp + 32);
      nx3 = *(const float4*)(xp + 36);
      const float* q = pn + (pt + 1) * 48 + ln * 3;
      npn0 = q[0]; npn1 = q[1]; npn2 = q[2];
    }

    const float px = p[pt * 3 + 0], py = p[pt * 3 + 1], pz = p[pt * 3 + 2];

    // A-fragments: row = neighbor (ln), k = 8g+j (+32 for chunk 1)
    u16x8 a0u, a1u;
#pragma unroll
    for (int j = 0; j < 8; ++j){ a0u[j] = f2bf(cx[j]); a1u[j] = f2bf(cx[8 + j]); }
    const bf16x8 a0 = __builtin_bit_cast(bf16x8, a0u);
    const bf16x8 a1 = __builtin_bit_cast(bf16x8, a1u);

    // pos fragment: A[row=neighbor][k<3] = p - pn, zero-padded to K=32
    u16x8 apu;
#pragma unroll
    for (int j = 0; j < 8; ++j) apu[j] = 0;
    if (g == 0){
      apu[0] = f2bf(px - pnx);
      apu[1] = f2bf(py - pny);
      apu[2] = f2bf(pz - pnz);
    }
    const bf16x8 ap = __builtin_bit_cast(bf16x8, apu);

    // ---- layer 1 (bias folded into acc init) ----
    f32x4 hk[4], hv[4], hp[4];
#pragma unroll
    for (int t = 0; t < 4; ++t){
      f32x4 c; c[0]=bk1[t]; c[1]=bk1[t]; c[2]=bk1[t]; c[3]=bk1[t];
      c = mfma16(a0, wk1[t][0], c); c = mfma16(a1, wk1[t][1], c); hk[t] = c;
      f32x4 d; d[0]=bv1[t]; d[1]=bv1[t]; d[2]=bv1[t]; d[3]=bv1[t];
      d = mfma16(a0, wv1[t][0], d); d = mfma16(a1, wv1[t][1], d); hv[t] = d;
      f32x4 e; e[0]=bp1[t]; e[1]=bp1[t]; e[2]=bp1[t]; e[3]=bp1[t];
      e = mfma16(ap, wp1t[t], e); hp[t] = e;
    }

    // ---- relu + bf16 + stage to LDS (C/D layout -> swizzled [n][ch]) ----
#pragma unroll
    for (int t = 0; t < 4; ++t){
      const int c = ln + 16 * t;
#pragma unroll
      for (int ii = 0; ii < 4; ++ii){
        const int r = 4 * g + ii;
        const int idx = r * 64 + (c ^ ((r & 7) << 3));
        sK[idx] = f2bf(fmaxf(hk[t][ii], 0.f));
        sV[idx] = f2bf(fmaxf(hv[t][ii], 0.f));
        sP[idx] = f2bf(fmaxf(hp[t][ii], 0.f));
      }
    }
    __syncthreads();

    // ---- read layer-2 A-fragments (ds_read_b128, swizzle-matched) ----
    const int rb = ln * 64;
    const int sw = (ln & 7) << 3;
    const bf16x8 fk0 = __builtin_bit_cast(bf16x8, *(const u16x8*)(sK + rb + (( 0 + 8 * g) ^ sw)));
    const bf16x8 fk1 = __builtin_bit_cast(bf16x8, *(const u16x8*)(sK + rb + ((32 + 8 * g) ^ sw)));
    const bf16x8 fv0 = __builtin_bit_cast(bf16x8, *(const u16x8*)(sV + rb + (( 0 + 8 * g) ^ sw)));
    const bf16x8 fv1 = __builtin_bit_cast(bf16x8, *(const u16x8*)(sV + rb + ((32 + 8 * g) ^ sw)));
    const bf16x8 fp0 = __builtin_bit_cast(bf16x8, *(const u16x8*)(sP + rb + (( 0 + 8 * g) ^ sw)));
    const bf16x8 fp1 = __builtin_bit_cast(bf16x8, *(const u16x8*)(sP + rb + ((32 + 8 * g) ^ sw)));

    // ---- layer 2 ----
    f32x4 kf[4], vf[4], pe[4];
#pragma unroll
    for (int t = 0; t < 4; ++t){
      f32x4 c; c[0]=bk2[t]; c[1]=bk2[t]; c[2]=bk2[t]; c[3]=bk2[t];
      c = mfma16(fk0, wk2[t][0], c); c = mfma16(fk1, wk2[t][1], c); kf[t] = c;
      f32x4 d; d[0]=bv2[t]; d[1]=bv2[t]; d[2]=bv2[t]; d[3]=bv2[t];
      d = mfma16(fv0, wv2[t][0], d); d = mfma16(fv1, wv2[t][1], d); vf[t] = d;
      f32x4 e; e[0]=bp2[t]; e[1]=bp2[t]; e[2]=bp2[t]; e[3]=bp2[t];
      e = mfma16(fp0, wp2[t][0], e); e = mfma16(fp1, wp2[t][1], e); pe[t] = e;
    }
    __syncthreads();   // protect staging buffers before next iteration's writes

    // ---- softmax over neighbors (Q dropped: shift-invariant) + output ----
    float o0, o1, o2, o3;
#pragma unroll
    for (int t = 0; t < 4; ++t){
      const float L0 = pe[t][0] - kf[t][0];
      const float L1 = pe[t][1] - kf[t][1];
      const float L2 = pe[t][2] - kf[t][2];
      const float L3 = pe[t][3] - kf[t][3];
      float m = fmaxf(fmaxf(L0, L1), fmaxf(L2, L3));
      m = fmaxf(m, __shfl_xor(m, 16));
      m = fmaxf(m, __shfl_xor(m, 32));
      const float lg2e = 1.4426950408889634f;
      const float w0 = exp2f((L0 - m) * lg2e);
      const float w1 = exp2f((L1 - m) * lg2e);
      const float w2 = exp2f((L2 - m) * lg2e);
      const float w3 = exp2f((L3 - m) * lg2e);
      float s = w0 + w1 + w2 + w3;
      float num = w0 * (vf[t][0] + pe[t][0]) + w1 * (vf[t][1] + pe[t][1])
                + w2 * (vf[t][2] + pe[t][2]) + w3 * (vf[t][3] + pe[t][3]);
      s   += __shfl_xor(s, 16);   s   += __shfl_xor(s, 32);
      num += __shfl_xor(num, 16); num += __shfl_xor(num, 32);
      const float ov = num * __builtin_amdgcn_rcpf(s);
      if (t == 0) o0 = ov; else if (t == 1) o1 = ov; else if (t == 2) o2 = ov; else o3 = ov;
    }
    const float val = (g == 0) ? o0 : (g == 1) ? o1 : (g == 2) ? o2 : o3;
    out[pt * 64 + lane] = val;
  }
}

extern "C" void kernel_launch(void* const* d_in, const int* in_sizes, int n_in,
                              void* d_out, int out_size, void* d_ws, size_t ws_size,
                              hipStream_t stream){
  (void)n_in; (void)d_ws; (void)ws_size; (void)out_size;
  const float* xn  = (const float*)d_in[1];
  const float* p   = (const float*)d_in[2];
  const float* pn  = (const float*)d_in[3];
  const float* kW1 = (const float*)d_in[8];
  const float* kb1 = (const float*)d_in[9];
  const float* kW2 = (const float*)d_in[10];
  const float* kb2 = (const float*)d_in[11];
  const float* vW1 = (const float*)d_in[12];
  const float* vb1 = (const float*)d_in[13];
  const float* vW2 = (const float*)d_in[14];
  const float* vb2 = (const float*)d_in[15];
  const float* pW1 = (const float*)d_in[16];
  const float* pb1 = (const float*)d_in[17];
  const float* pW2 = (const float*)d_in[18];
  const float* pb2 = (const float*)d_in[19];
  float* o = (float*)d_out;

  const int BN = in_sizes[1] / (16 * 64);   // B*N = 32768
  dim3 grid(BN / PTS_PER_BLOCK);
  hipLaunchKernelGGL(pt_fused, grid, dim3(64), 0, stream,
                     xn, p, pn, kW1, kb1, kW2, kb2,
                     vW1, vb1, vW2, vb2, pW1, pb1, pW2, pb2, o);
}

// Round 2
// 97.424 us; speedup vs baseline: 1.0088x; 1.0088x over previous
//
#include <hip/hip_runtime.h>

typedef __bf16 bf16x8 __attribute__((ext_vector_type(8)));
typedef float f32x4 __attribute__((ext_vector_type(4)));
typedef unsigned short u16x8 __attribute__((ext_vector_type(8)));
typedef unsigned short u16x4 __attribute__((ext_vector_type(4)));

static __device__ __forceinline__ unsigned short f2bf(float f){
  __bf16 h = (__bf16)f;
  return __builtin_bit_cast(unsigned short, h);
}
static __device__ __forceinline__ f32x4 mfma16(bf16x8 a, bf16x8 b, f32x4 c){
  return __builtin_amdgcn_mfma_f32_16x16x32_bf16(a, b, c, 0, 0, 0);
}

#define PTS 16

// ---------------- prep kernel: build bf16 weight fragments in ws ----------------
// ws layout (u16 units): frags [m][t*2+cc][lane] as u16x8, m: 0=kW1,1=vW1,2=kW2,3=vW2,4=pW2
//   -> 40 frags * 64 lanes * 8 u16.  Then wp1-compact: 64 entries * 4 u16
//   entry[ch] = {pW1[0][ch], pW1[1][ch], pW1[2][ch], pb1[ch]}   (bias rides k=3)
__global__ void pt_prep(const float* __restrict__ kW1, const float* __restrict__ vW1,
                        const float* __restrict__ kW2, const float* __restrict__ vW2,
                        const float* __restrict__ pW2, const float* __restrict__ pW1,
                        const float* __restrict__ pb1, unsigned short* __restrict__ ws){
  const int b = blockIdx.x, lane = threadIdx.x;
  if (b < 40){
    const float* W = (b < 8) ? kW1 : (b < 16) ? vW1 : (b < 24) ? kW2 : (b < 32) ? vW2 : pW2;
    const int f = b & 7, t = f >> 1, cc = f & 1;
    const int col = (lane & 15) + 16 * t;
    const int k0  = 8 * (lane >> 4) + 32 * cc;
    u16x8 v;
#pragma unroll
    for (int j = 0; j < 8; ++j) v[j] = f2bf(W[(k0 + j) * 64 + col]);
    *(u16x8*)(ws + (size_t)(b * 64 + lane) * 8) = v;
  } else {
    u16x4 v;
    v[0] = f2bf(pW1[lane]); v[1] = f2bf(pW1[64 + lane]);
    v[2] = f2bf(pW1[128 + lane]); v[3] = f2bf(pb1[lane]);
    *(u16x4*)(ws + 40 * 64 * 8 + lane * 4) = v;
  }
}

// ---------------- main fused kernel ----------------
__global__ __launch_bounds__(64, 2) void pt_fused(
    const float* __restrict__ xn, const float* __restrict__ p, const float* __restrict__ pn,
    const float* __restrict__ kb1, const float* __restrict__ vb1,
    const float* __restrict__ kb2, const float* __restrict__ vb2, const float* __restrict__ pb2,
    const unsigned short* __restrict__ ws, float* __restrict__ out)
{
  const int lane = threadIdx.x, ln = lane & 15, g = lane >> 4;

  __shared__ unsigned short sBuf[2][3][1024];   // [buf][K,V,P][n*64 + swizzled ch]
  __shared__ u16x8 sWp2[8][64];                 // pW2 fragments
  __shared__ unsigned short sWp1c[256];         // wp1 compact (64 ch x 4)
  __shared__ float sBias[128];                  // kb1[64], vb1[64]

  // ---- prologue: weights (coalesced b128 from ws) ----
  bf16x8 wk1[4][2], wv1[4][2], wk2[4][2], wv2[4][2];
#pragma unroll
  for (int t = 0; t < 4; ++t)
#pragma unroll
    for (int cc = 0; cc < 2; ++cc){
      const int f = t * 2 + cc;
      wk1[t][cc] = __builtin_bit_cast(bf16x8, *(const u16x8*)(ws + (size_t)(( 0 + f) * 64 + lane) * 8));
      wv1[t][cc] = __builtin_bit_cast(bf16x8, *(const u16x8*)(ws + (size_t)(( 8 + f) * 64 + lane) * 8));
      wk2[t][cc] = __builtin_bit_cast(bf16x8, *(const u16x8*)(ws + (size_t)((16 + f) * 64 + lane) * 8));
      wv2[t][cc] = __builtin_bit_cast(bf16x8, *(const u16x8*)(ws + (size_t)((24 + f) * 64 + lane) * 8));
      sWp2[f][lane] = *(const u16x8*)(ws + (size_t)((32 + f) * 64 + lane) * 8);
    }
  { uint2 t2 = *(const uint2*)(ws + 40 * 64 * 8 + lane * 4);
    *(uint2*)(sWp1c + lane * 4) = t2; }
  sBias[lane] = kb1[lane]; sBias[64 + lane] = vb1[lane];

  float bk2[4], bv2[4], bp2[4];
#pragma unroll
  for (int t = 0; t < 4; ++t){
    const int c = ln + 16 * t;
    bk2[t] = kb2[c]; bv2[t] = vb2[c]; bp2[t] = pb2[c];
  }

  const size_t p0 = (size_t)blockIdx.x * PTS;
  const size_t xbase = p0 * 1024 + (size_t)ln * 64 + g * 8;

  float4 nx0, nx1, nx2, nx3; float np0, np1, np2;

#define PREF(j) { const float* xp = xn + xbase + (size_t)(j) * 1024;                         \
    nx0 = *(const float4*)(xp);      nx1 = *(const float4*)(xp + 4);                         \
    nx2 = *(const float4*)(xp + 32); nx3 = *(const float4*)(xp + 36);                        \
    const float* q = pn + (p0 + (j)) * 48 + ln * 3; np0 = q[0]; np1 = q[1]; np2 = q[2]; }

  // stage A: L1 (swapped operands -> [ch][n] layout) for point j, write buf bp
  auto stageA = [&](int j, int bp, bool pref){
    const size_t pt = p0 + j;
    const float px = p[pt * 3 + 0], py = p[pt * 3 + 1], pz = p[pt * 3 + 2];
    u16x8 a0u, a1u;
    a0u[0]=f2bf(nx0.x); a0u[1]=f2bf(nx0.y); a0u[2]=f2bf(nx0.z); a0u[3]=f2bf(nx0.w);
    a0u[4]=f2bf(nx1.x); a0u[5]=f2bf(nx1.y); a0u[6]=f2bf(nx1.z); a0u[7]=f2bf(nx1.w);
    a1u[0]=f2bf(nx2.x); a1u[1]=f2bf(nx2.y); a1u[2]=f2bf(nx2.z); a1u[3]=f2bf(nx2.w);
    a1u[4]=f2bf(nx3.x); a1u[5]=f2bf(nx3.y); a1u[6]=f2bf(nx3.z); a1u[7]=f2bf(nx3.w);
    const float dx = px - np0, dy = py - np1, dz = pz - np2;
    u16x8 apu = {0,0,0,0,0,0,0,0};
    if (g == 0){ apu[0]=f2bf(dx); apu[1]=f2bf(dy); apu[2]=f2bf(dz); apu[3]=0x3F80u; }
    const bf16x8 a0 = __builtin_bit_cast(bf16x8, a0u);
    const bf16x8 a1 = __builtin_bit_cast(bf16x8, a1u);
    const bf16x8 ap = __builtin_bit_cast(bf16x8, apu);
    if (pref) PREF(j + 1);

    unsigned short* bK = &sBuf[bp][0][0];
    unsigned short* bV = &sBuf[bp][1][0];
    unsigned short* bP = &sBuf[bp][2][0];
    const int swz = (ln & 7) << 3;
#pragma unroll
    for (int t = 0; t < 4; ++t){
      f32x4 hk = *(const f32x4*)(sBias + 16 * t + 4 * g);
      hk = mfma16(wk1[t][0], a0, hk); hk = mfma16(wk1[t][1], a1, hk);
      f32x4 hv = *(const f32x4*)(sBias + 64 + 16 * t + 4 * g);
      hv = mfma16(wv1[t][0], a0, hv); hv = mfma16(wv1[t][1], a1, hv);
      u16x8 w1u = {0,0,0,0,0,0,0,0};
      if (g == 0){
        const int e = (16 * t + ln) * 4;
        w1u[0] = sWp1c[e]; w1u[1] = sWp1c[e + 1]; w1u[2] = sWp1c[e + 2]; w1u[3] = sWp1c[e + 3];
      }
      f32x4 z = {0.f, 0.f, 0.f, 0.f};
      f32x4 hp = mfma16(__builtin_bit_cast(bf16x8, w1u), ap, z);

      const int wa = ln * 64 + ((16 * t + 4 * g) ^ swz);
      u16x4 qk, qv, qp;
#pragma unroll
      for (int ii = 0; ii < 4; ++ii){
        qk[ii] = f2bf(fmaxf(hk[ii], 0.f));
        qv[ii] = f2bf(fmaxf(hv[ii], 0.f));
        qp[ii] = f2bf(fmaxf(hp[ii], 0.f));
      }
      *(u16x4*)(bK + wa) = qk; *(u16x4*)(bV + wa) = qv; *(u16x4*)(bP + wa) = qp;
    }
  };

  // stage B: L2 + softmax + store for point j from buf bp
  auto stageB = [&](int j, int bp){
    const size_t pt = p0 + j;
    const unsigned short* bK = &sBuf[bp][0][0];
    const unsigned short* bV = &sBuf[bp][1][0];
    const unsigned short* bP = &sBuf[bp][2][0];
    const int rb = ln * 64, swz = (ln & 7) << 3;
    const int o0 = (8 * g) ^ swz, o1 = (8 * g + 32) ^ swz;
    const bf16x8 fk0 = __builtin_bit_cast(bf16x8, *(const u16x8*)(bK + rb + o0));
    const bf16x8 fk1 = __builtin_bit_cast(bf16x8, *(const u16x8*)(bK + rb + o1));
    const bf16x8 fv0 = __builtin_bit_cast(bf16x8, *(const u16x8*)(bV + rb + o0));
    const bf16x8 fv1 = __builtin_bit_cast(bf16x8, *(const u16x8*)(bV + rb + o1));
    const bf16x8 fp0 = __builtin_bit_cast(bf16x8, *(const u16x8*)(bP + rb + o0));
    const bf16x8 fp1 = __builtin_bit_cast(bf16x8, *(const u16x8*)(bP + rb + o1));
    float oval = 0.f;
#pragma unroll
    for (int t = 0; t < 4; ++t){
      f32x4 kf = {bk2[t], bk2[t], bk2[t], bk2[t]};
      kf = mfma16(fk0, wk2[t][0], kf); kf = mfma16(fk1, wk2[t][1], kf);
      f32x4 vf = {bv2[t], bv2[t], bv2[t], bv2[t]};
      vf = mfma16(fv0, wv2[t][0], vf); vf = mfma16(fv1, wv2[t][1], vf);
      const bf16x8 wp0 = __builtin_bit_cast(bf16x8, sWp2[2 * t][lane]);
      const bf16x8 wp1 = __builtin_bit_cast(bf16x8, sWp2[2 * t + 1][lane]);
      f32x4 pe = {bp2[t], bp2[t], bp2[t], bp2[t]};
      pe = mfma16(fp0, wp0, pe); pe = mfma16(fp1, wp1, pe);

      const float L0 = pe[0] - kf[0], L1 = pe[1] - kf[1];
      const float L2 = pe[2] - kf[2], L3 = pe[3] - kf[3];
      float m = fmaxf(fmaxf(L0, L1), fmaxf(L2, L3));
      m = fmaxf(m, __shfl_xor(m, 16));
      m = fmaxf(m, __shfl_xor(m, 32));
      const float c = 1.4426950408889634f;
      const float w0 = exp2f((L0 - m) * c), w1 = exp2f((L1 - m) * c);
      const float w2 = exp2f((L2 - m) * c), w3 = exp2f((L3 - m) * c);
      float s = w0 + w1 + w2 + w3;
      float num = w0 * (vf[0] + pe[0]) + w1 * (vf[1] + pe[1])
                + w2 * (vf[2] + pe[2]) + w3 * (vf[3] + pe[3]);
      s   += __shfl_xor(s, 16);   s   += __shfl_xor(s, 32);
      num += __shfl_xor(num, 16); num += __shfl_xor(num, 32);
      const float res = num * __builtin_amdgcn_rcpf(s);
      oval = (g == t) ? res : oval;
    }
    out[pt * 64 + lane] = oval;
  };

  PREF(0);
  stageA(0, 0, true);
#pragma unroll 2
  for (int i = 0; i < PTS; ++i){
    asm volatile("" ::: "memory");   // keep LDS/bias reads per-iteration (stop LICM reg blowup)
    if (i + 1 < PTS) stageA(i + 1, (i + 1) & 1, i + 2 < PTS);
    stageB(i, i & 1);
  }
#undef PREF
}

extern "C" void kernel_launch(void* const* d_in, const int* in_sizes, int n_in,
                              void* d_out, int out_size, void* d_ws, size_t ws_size,
                              hipStream_t stream){
  (void)n_in; (void)ws_size; (void)out_size;
  const float* xn  = (const float*)d_in[1];
  const float* p   = (const float*)d_in[2];
  const float* pn  = (const float*)d_in[3];
  const float* kW1 = (const float*)d_in[8];
  const float* kb1 = (const float*)d_in[9];
  const float* kW2 = (const float*)d_in[10];
  const float* kb2 = (const float*)d_in[11];
  const float* vW1 = (const float*)d_in[12];
  const float* vb1 = (const float*)d_in[13];
  const float* vW2 = (const float*)d_in[14];
  const float* vb2 = (const float*)d_in[15];
  const float* pW1 = (const float*)d_in[16];
  const float* pb1 = (const float*)d_in[17];
  const float* pW2 = (const float*)d_in[18];
  const float* pb2 = (const float*)d_in[19];
  unsigned short* ws = (unsigned short*)d_ws;
  float* o = (float*)d_out;

  hipLaunchKernelGGL(pt_prep, dim3(41), dim3(64), 0, stream,
                     kW1, vW1, kW2, vW2, pW2, pW1, pb1, ws);

  const int BN = in_sizes[1] / (16 * 64);   // B*N = 32768
  dim3 grid(BN / PTS);
  hipLaunchKernelGGL(pt_fused, grid, dim3(64), 0, stream,
                     xn, p, pn, kb1, vb1, kb2, vb2, pb2, ws, o);
}